// Round 9
// baseline (124.861 us; speedup 1.0000x reference)
//
#include <hip/hip_runtime.h>
#include <hip/hip_bf16.h>
#include <cstdint>

typedef __attribute__((ext_vector_type(4))) float f32x4;
typedef __attribute__((ext_vector_type(8))) short s16x8;

#define NB   32
#define NL   2048
#define NH   512
#define NM   (NB * NL)          // 65536 rows
#define SCALE 0.04419417382415922f  // 1/sqrt(512)

__device__ __forceinline__ ushort f2bf(float f) {
    __hip_bfloat16 b = __float2bfloat16(f);   // pairs fuse into v_cvt_pk_bf16_f32
    return *reinterpret_cast<ushort*>(&b);
}
__device__ __forceinline__ unsigned long long pack4(float4 f) {
    union { ushort u[4]; unsigned long long v; } p;
    p.u[0] = f2bf(f.x); p.u[1] = f2bf(f.y); p.u[2] = f2bf(f.z); p.u[3] = f2bf(f.w);
    return p.v;
}

// async global->LDS, 16B/lane: dest = wave-uniform base + lane*16; global addr per-lane
#define GL16(g, l)                                                         \
    __builtin_amdgcn_global_load_lds(                                      \
        (const __attribute__((address_space(1))) unsigned int*)(g),        \
        (__attribute__((address_space(3))) unsigned int*)(l), 16, 0, 0)

// ============================================================================
// k_pre: convW (blocks 0..63) + eq (blocks 64..95)
// ============================================================================
__global__ __launch_bounds__(256) void k_pre(const float* __restrict__ W,
                                             ushort* __restrict__ Wb,
                                             const float* __restrict__ query,
                                             const float* __restrict__ Wq,
                                             float* __restrict__ eq) {
    int bid = blockIdx.x;
    int t = threadIdx.x;
    if (bid < 64) {
        const float4* F = (const float4*)W;
        unsigned long long* U = (unsigned long long*)Wb;
        int base = bid * 1024 + t;
        float4 f[4];
#pragma unroll
        for (int k = 0; k < 4; ++k) f[k] = F[base + k * 256];
#pragma unroll
        for (int k = 0; k < 4; ++k) U[base + k * 256] = pack4(f[k]);
    } else {
        __shared__ float q[NH];
        int b = bid - 64;
        q[t] = query[b * NH + t];
        q[t + 256] = query[b * NH + t + 256];
        __syncthreads();
#pragma unroll
        for (int half = 0; half < 2; ++half) {
            int o = t + half * 256;
            const float4* w = (const float4*)(Wq + (size_t)o * NH);
            float acc = 0.f;
#pragma unroll 4
            for (int i = 0; i < NH / 4; ++i) {
                float4 x = w[i];
                acc += q[4 * i] * x.x + q[4 * i + 1] * x.y + q[4 * i + 2] * x.z + q[4 * i + 3] * x.w;
            }
            eq[b * NH + o] = acc;
        }
    }
}

// ============================================================================
// k_gemm_full: full-N score GEMM. 1024 blocks x 512 thr.
// BM=64, BN=512, BK=32, 16 K-steps, 8 waves (each 64 rows x 64 cols, 4x4 frags).
// ALL staging via global_load_lds: B bf16 [512][32] (4/wave), A f32 [64][32] (1/wave).
// XOR chunk-swizzle both-sides (pre-swizzled global lane addr + swizzled read).
// A cvt f32->bf16 in-register after ds_read (overlaps MFMA). One barrier/phase.
// ============================================================================
__global__ __launch_bounds__(512, 4) void k_gemm_full(const float* __restrict__ ref,
                                                      const ushort* __restrict__ Wb,
                                                      const float* __restrict__ eq,
                                                      const float* __restrict__ v,
                                                      const int* __restrict__ mask,
                                                      float* __restrict__ out_sc) {
    __shared__ char smem[81920];                 // 80 KB exactly -> 2 blocks/CU
    ushort* Bs0 = (ushort*)smem;                 // 32 KB
    ushort* Bs1 = (ushort*)(smem + 32768);       // 32 KB
    float*  As0 = (float*)(smem + 65536);        // 8 KB
    float*  As1 = (float*)(smem + 73728);        // 8 KB

    int tid = threadIdx.x;
    int lane = tid & 63, wid = tid >> 6;
    int blk = blockIdx.x;
    int m0g = blk << 6;                          // 64 rows/block
    int b = blk >> 5;                            // batch

    f32x4 acc[4][4];
#pragma unroll
    for (int i = 0; i < 4; ++i)
#pragma unroll
        for (int j = 0; j < 4; ++j) acc[i][j] = (f32x4)(0.f);

    // ---- B staging addr (pre-swizzled chunk: (l&3)^((l>>3)&3)) ----
    const ushort* bglob = Wb + ((size_t)(wid * 64) + (lane >> 2)) * NH
                             + (((lane & 3) ^ ((lane >> 3) & 3)) << 3);
    // ---- A staging addr (pre-swizzled chunk: (l&7)^((l>>3)&7)), f32 ----
    const float* aglob = ref + (size_t)(m0g + wid * 8 + (lane >> 3)) * NH
                             + (((lane & 7) ^ ((lane >> 3) & 7)) << 2);

    int lr = lane & 15, kq = lane >> 4;
    // B read base (swizzled): row (wid*64+lr), chunk kq^((lr>>1)&3)
    int bbase = (wid * 64 + lr) * 32 + ((kq ^ ((lr >> 1) & 3)) << 3);
    // A read (swizzled, f32): row lr (+fr*16), chunks (2kq+h)^(lr&7)
    int arow = lr * 32;
    int ac0 = (((2 * kq) ^ (lr & 7)) << 2);
    int ac1 = (((2 * kq + 1) ^ (lr & 7)) << 2);

#define STAGE(Bsb, Asb, kt)                                           \
    {   GL16(bglob + (kt) * 32,            Bsb + (wid * 64) * 32);    \
        GL16(bglob + (kt) * 32 + 16 * NH,  Bsb + (wid * 64 + 16) * 32); \
        GL16(bglob + (kt) * 32 + 32 * NH,  Bsb + (wid * 64 + 32) * 32); \
        GL16(bglob + (kt) * 32 + 48 * NH,  Bsb + (wid * 64 + 48) * 32); \
        GL16(aglob + (kt) * 32,            Asb + (wid * 8) * 32); }

#define READ_COMPUTE(Bsb, Asb)                                                   \
    {   s16x8 bfr[4], af[4];                                                     \
        _Pragma("unroll")                                                        \
        for (int f = 0; f < 4; ++f) bfr[f] = *(const s16x8*)&Bsb[bbase + f * 512]; \
        _Pragma("unroll")                                                        \
        for (int f = 0; f < 4; ++f) {                                            \
            float4 a0 = *(const float4*)(Asb + arow + f * 512 + ac0);            \
            float4 a1 = *(const float4*)(Asb + arow + f * 512 + ac1);            \
            union { ushort u[8]; s16x8 v; } p;                                   \
            p.u[0] = f2bf(a0.x); p.u[1] = f2bf(a0.y);                            \
            p.u[2] = f2bf(a0.z); p.u[3] = f2bf(a0.w);                            \
            p.u[4] = f2bf(a1.x); p.u[5] = f2bf(a1.y);                            \
            p.u[6] = f2bf(a1.z); p.u[7] = f2bf(a1.w);                            \
            af[f] = p.v;                                                         \
        }                                                                        \
        _Pragma("unroll")                                                        \
        for (int fr = 0; fr < 4; ++fr)                                           \
            _Pragma("unroll")                                                    \
            for (int fc = 0; fc < 4; ++fc)                                       \
                acc[fr][fc] = __builtin_amdgcn_mfma_f32_16x16x32_bf16(           \
                    af[fr], bfr[fc], acc[fr][fc], 0, 0, 0);                      \
    }

    // prologue: K-step 0 -> buf0
    STAGE(Bs0, As0, 0)
    __syncthreads();

    for (int t2 = 0; t2 < 8; ++t2) {
        int k0 = 2 * t2;
        // phase A: stage k0+1 -> buf1 (in flight across compute); compute k0 from buf0
        STAGE(Bs1, As1, k0 + 1)
        READ_COMPUTE(Bs0, As0)
        __syncthreads();
        // phase B: stage k0+2 -> buf0; compute k0+1 from buf1
        if (k0 + 2 < 16) STAGE(Bs0, As0, k0 + 2)
        READ_COMPUTE(Bs1, As1)
        __syncthreads();
    }
#undef STAGE
#undef READ_COMPUTE

    // ---- epilogue: full score rows (sc_red overlays Bs0 after last barrier) ----
    float* sc_red = (float*)smem;                // [8][64]
    const float* eqb = eq + b * NH;
    float vv[4], ee[4];
#pragma unroll
    for (int fc = 0; fc < 4; ++fc) {
        int c = wid * 64 + fc * 16 + lr;
        vv[fc] = v[c];
        ee[fc] = eqb[c];
    }
#pragma unroll
    for (int fr = 0; fr < 4; ++fr) {
#pragma unroll
        for (int reg = 0; reg < 4; ++reg) {
            float s = 0.f;
#pragma unroll
            for (int fc = 0; fc < 4; ++fc) {
                float x = acc[fr][fc][reg] + ee[fc];
                float t = 1.f - 2.f / (__expf(2.f * x) + 1.f);  // tanh
                s += vv[fc] * t;
            }
            s += __shfl_xor(s, 1);
            s += __shfl_xor(s, 2);
            s += __shfl_xor(s, 4);
            s += __shfl_xor(s, 8);
            if (lr == 0) sc_red[wid * 64 + fr * 16 + kq * 4 + reg] = s;
        }
    }
    __syncthreads();
    if (tid < 64) {
        float t = 0.f;
#pragma unroll
        for (int w = 0; w < 8; ++w) t += sc_red[w * 64 + tid];
        t *= SCALE;
        int rg = m0g + tid;
        if (mask[rg] != 0) t = -1e9f;
        out_sc[rg] = t;
    }
}

// ============================================================================
// k_smglp: softmax (from final scores) + glimpse slice. grid (16 sp, 32 b).
// ============================================================================
__global__ __launch_bounds__(256) void k_smglp(const float* __restrict__ scores,
                                               const float* __restrict__ ref,
                                               float* __restrict__ glp) {
    int sp = blockIdx.x, b = blockIdx.y;
    int tid = threadIdx.x;
    int lane = tid & 63, wid = tid >> 6;
    __shared__ float red[4];
    __shared__ float asl[128];    // unnormalized exp for rows sp*128..+128
    float sc[8];
    float mx = -3.4e38f;
#pragma unroll
    for (int i = 0; i < 8; ++i) {
        sc[i] = scores[b * NL + i * 256 + tid];
        mx = fmaxf(mx, sc[i]);
    }
#pragma unroll
    for (int o = 32; o >= 1; o >>= 1) mx = fmaxf(mx, __shfl_xor(mx, o));
    if (lane == 0) red[wid] = mx;
    __syncthreads();
    mx = fmaxf(fmaxf(red[0], red[1]), fmaxf(red[2], red[3]));
    __syncthreads();
    float ls = 0.f;
#pragma unroll
    for (int i = 0; i < 8; ++i) {
        float e = __expf(sc[i] - mx);
        ls += e;
        if (i == (sp >> 1) && (tid >> 7) == (sp & 1)) asl[tid & 127] = e;
    }
#pragma unroll
    for (int o = 32; o >= 1; o >>= 1) ls += __shfl_xor(ls, o);
    if (lane == 0) red[wid] = ls;
    __syncthreads();
    float inv = 1.f / (red[0] + red[1] + red[2] + red[3]);

    const float* rb = ref + ((size_t)b * NL + sp * 128) * NH;
    float2 acc = make_float2(0.f, 0.f);
#pragma unroll 4
    for (int l = 0; l < 128; ++l) {
        float a = asl[l];
        float2 r = ((const float2*)(rb + (size_t)l * NH))[tid];
        acc.x += a * r.x;
        acc.y += a * r.y;
    }
    acc.x *= inv;
    acc.y *= inv;
    ((float2*)(glp + (size_t)(sp * NB + b) * NH))[tid] = acc;
}

// ---- reduce glimpse partials (16 splits) ----
__global__ __launch_bounds__(256) void k_gred(const float* __restrict__ glp,
                                              float* __restrict__ out_gl) {
    int idx = blockIdx.x * 256 + threadIdx.x;   // 16384 = B*H
    float s = 0.f;
#pragma unroll
    for (int sp = 0; sp < 16; ++sp) s += glp[sp * (NB * NH) + idx];
    out_gl[idx] = s;
}

extern "C" void kernel_launch(void* const* d_in, const int* in_sizes, int n_in,
                              void* d_out, int out_size, void* d_ws, size_t ws_size,
                              hipStream_t stream) {
    const float* query = (const float*)d_in[0];
    const float* ref   = (const float*)d_in[1];
    const int*   mask  = (const int*)d_in[2];
    const float* W_ref = (const float*)d_in[3];
    const float* W_q   = (const float*)d_in[4];
    const float* v     = (const float*)d_in[5];

    float* out_gl = (float*)d_out;              // 32*512
    float* out_sc = out_gl + NB * NH;           // 32*2048 (final scores)

    char* w = (char*)d_ws;
    ushort* wW = (ushort*)w;                    // 524,288 B @ 0
    float* eq  = (float*)(w + 524288);          // 65,536 B
    float* glp = (float*)(w + 589824);          // 16*32*512*4 = 1,048,576 B

    k_pre<<<96, 256, 0, stream>>>(W_ref, wW, query, W_q, eq);
    k_gemm_full<<<1024, 512, 0, stream>>>(ref, wW, eq, v, mask, out_sc);
    k_smglp<<<dim3(16, NB), 256, 0, stream>>>(out_sc, ref, glp);
    k_gred<<<64, 256, 0, stream>>>(glp, out_gl);
}

// Round 10
// 120.677 us; speedup vs baseline: 1.0347x; 1.0347x over previous
//
#include <hip/hip_runtime.h>
#include <hip/hip_bf16.h>
#include <cstdint>

typedef __attribute__((ext_vector_type(4))) float f32x4;
typedef __attribute__((ext_vector_type(8))) short s16x8;

#define NB   32
#define NL   2048
#define NH   512
#define NM   (NB * NL)          // 65536 rows
#define SCALE 0.04419417382415922f  // 1/sqrt(512)

__device__ __forceinline__ ushort f2bf(float f) {
    __hip_bfloat16 b = __float2bfloat16(f);   // pairs fuse into v_cvt_pk_bf16_f32
    return *reinterpret_cast<ushort*>(&b);
}
__device__ __forceinline__ unsigned long long pack4(float4 f) {
    union { ushort u[4]; unsigned long long v; } p;
    p.u[0] = f2bf(f.x); p.u[1] = f2bf(f.y); p.u[2] = f2bf(f.z); p.u[3] = f2bf(f.w);
    return p.v;
}

// async global->LDS, 16B/lane: dest = wave-uniform base + lane*16; global addr per-lane
#define GL16(g, l)                                                         \
    __builtin_amdgcn_global_load_lds(                                      \
        (const __attribute__((address_space(1))) unsigned int*)(g),        \
        (__attribute__((address_space(3))) unsigned int*)(l), 16, 0, 0)

// ============================================================================
// k_pre: convW (blocks 0..63) + eq (blocks 64..95)
// ============================================================================
__global__ __launch_bounds__(256) void k_pre(const float* __restrict__ W,
                                             ushort* __restrict__ Wb,
                                             const float* __restrict__ query,
                                             const float* __restrict__ Wq,
                                             float* __restrict__ eq) {
    int bid = blockIdx.x;
    int t = threadIdx.x;
    if (bid < 64) {
        const float4* F = (const float4*)W;
        unsigned long long* U = (unsigned long long*)Wb;
        int base = bid * 1024 + t;
        float4 f[4];
#pragma unroll
        for (int k = 0; k < 4; ++k) f[k] = F[base + k * 256];
#pragma unroll
        for (int k = 0; k < 4; ++k) U[base + k * 256] = pack4(f[k]);
    } else {
        __shared__ float q[NH];
        int b = bid - 64;
        q[t] = query[b * NH + t];
        q[t + 256] = query[b * NH + t + 256];
        __syncthreads();
#pragma unroll
        for (int half = 0; half < 2; ++half) {
            int o = t + half * 256;
            const float4* w = (const float4*)(Wq + (size_t)o * NH);
            float acc = 0.f;
#pragma unroll 4
            for (int i = 0; i < NH / 4; ++i) {
                float4 x = w[i];
                acc += q[4 * i] * x.x + q[4 * i + 1] * x.y + q[4 * i + 2] * x.z + q[4 * i + 3] * x.w;
            }
            eq[b * NH + o] = acc;
        }
    }
}

// ============================================================================
// k_gemm_full: full-N score GEMM. 1024 blocks x 512 thr.
// BM=64, BN=512, BK=32, 16 K-steps, 8 waves (each 64 rows x 64 cols, 4x4 frags).
// ALL staging via global_load_lds. T3/T4: counted vmcnt (never drain to 0 in
// the main loop), raw s_barrier pairs, setprio around MFMA cluster.
// Phase: wait vmcnt(5); bar; ds_read+cvt; lgkmcnt(0); bar; STAGE(+5); MFMA.
// ============================================================================
__global__ __launch_bounds__(512, 4) void k_gemm_full(const float* __restrict__ ref,
                                                      const ushort* __restrict__ Wb,
                                                      const float* __restrict__ eq,
                                                      const float* __restrict__ v,
                                                      const int* __restrict__ mask,
                                                      float* __restrict__ out_sc) {
    __shared__ char smem[81920];                 // 80 KB -> 2 blocks/CU
    ushort* Bs0 = (ushort*)smem;                 // 32 KB
    ushort* Bs1 = (ushort*)(smem + 32768);       // 32 KB
    float*  As0 = (float*)(smem + 65536);        // 8 KB
    float*  As1 = (float*)(smem + 73728);        // 8 KB

    int tid = threadIdx.x;
    int lane = tid & 63, wid = tid >> 6;
    int blk = blockIdx.x;
    int m0g = blk << 6;                          // 64 rows/block
    int b = blk >> 5;                            // batch

    f32x4 acc[4][4];
#pragma unroll
    for (int i = 0; i < 4; ++i)
#pragma unroll
        for (int j = 0; j < 4; ++j) acc[i][j] = (f32x4)(0.f);

    // ---- B staging addr (linear chunks; wave stages its own read region) ----
    const ushort* bglob = Wb + ((size_t)(wid * 64) + (lane >> 2)) * NH + ((lane & 3) << 3);
    // ---- A staging addr (pre-swizzled chunk: (l&7)^((l>>3)&7)), f32 ----
    const float* aglob = ref + (size_t)(m0g + wid * 8 + (lane >> 3)) * NH
                             + (((lane & 7) ^ ((lane >> 3) & 7)) << 2);

    int lr = lane & 15, kq = lane >> 4;
    // B read base: row (wid*64+lr), chunk kq  (structural-min banking for b128)
    int bbase = (wid * 64 + lr) * 32 + (kq << 3);
    // A read (swizzled, f32): row lr (+fr*16), chunks (2kq+h)^(lr&7)
    int arow = lr * 32;
    int ac0 = (((2 * kq) ^ (lr & 7)) << 2);
    int ac1 = (((2 * kq + 1) ^ (lr & 7)) << 2);

#define STAGE(Bsb, Asb, kt)                                           \
    {   GL16(bglob + (kt) * 32,            Bsb + (wid * 64) * 32);    \
        GL16(bglob + (kt) * 32 + 16 * NH,  Bsb + (wid * 64 + 16) * 32); \
        GL16(bglob + (kt) * 32 + 32 * NH,  Bsb + (wid * 64 + 32) * 32); \
        GL16(bglob + (kt) * 32 + 48 * NH,  Bsb + (wid * 64 + 48) * 32); \
        GL16(aglob + (kt) * 32,            Asb + (wid * 8) * 32); }

#define READ_CVT(Bsb, Asb)                                                       \
    _Pragma("unroll")                                                            \
    for (int f = 0; f < 4; ++f) bfr[f] = *(const s16x8*)&Bsb[bbase + f * 512];   \
    _Pragma("unroll")                                                            \
    for (int f = 0; f < 4; ++f) {                                                \
        float4 a0 = *(const float4*)(Asb + arow + f * 512 + ac0);                \
        float4 a1 = *(const float4*)(Asb + arow + f * 512 + ac1);                \
        union { ushort u[8]; s16x8 v; } p;                                       \
        p.u[0] = f2bf(a0.x); p.u[1] = f2bf(a0.y);                                \
        p.u[2] = f2bf(a0.z); p.u[3] = f2bf(a0.w);                                \
        p.u[4] = f2bf(a1.x); p.u[5] = f2bf(a1.y);                                \
        p.u[6] = f2bf(a1.z); p.u[7] = f2bf(a1.w);                                \
        af[f] = p.v;                                                             \
    }

#define MFMA_ALL()                                                               \
    __builtin_amdgcn_s_setprio(1);                                               \
    _Pragma("unroll")                                                            \
    for (int fr = 0; fr < 4; ++fr)                                               \
        _Pragma("unroll")                                                        \
        for (int fc = 0; fc < 4; ++fc)                                           \
            acc[fr][fc] = __builtin_amdgcn_mfma_f32_16x16x32_bf16(               \
                af[fr], bfr[fc], acc[fr][fc], 0, 0, 0);                          \
    __builtin_amdgcn_s_setprio(0);

    // prologue: two K-steps in flight (10 vmem ops/wave)
    STAGE(Bs0, As0, 0)
    STAGE(Bs1, As1, 1)

    // main loop: k = 0..13, counted vmcnt, two raw barriers per phase
#pragma unroll 1
    for (int t2 = 0; t2 < 7; ++t2) {
        {   // phase A: compute k=2*t2 from buf0, restage buf0 with k+2
            s16x8 bfr[4], af[4];
            asm volatile("s_waitcnt vmcnt(5)" ::: "memory");
            __builtin_amdgcn_s_barrier();
            READ_CVT(Bs0, As0)
            asm volatile("s_waitcnt lgkmcnt(0)" ::: "memory");
            __builtin_amdgcn_sched_barrier(0);
            __builtin_amdgcn_s_barrier();
            STAGE(Bs0, As0, 2 * t2 + 2)
            MFMA_ALL()
        }
        {   // phase B: compute k=2*t2+1 from buf1, restage buf1 with k+3
            s16x8 bfr[4], af[4];
            asm volatile("s_waitcnt vmcnt(5)" ::: "memory");
            __builtin_amdgcn_s_barrier();
            READ_CVT(Bs1, As1)
            asm volatile("s_waitcnt lgkmcnt(0)" ::: "memory");
            __builtin_amdgcn_sched_barrier(0);
            __builtin_amdgcn_s_barrier();
            STAGE(Bs1, As1, 2 * t2 + 3)
            MFMA_ALL()
        }
    }
    {   // k=14: no restage
        s16x8 bfr[4], af[4];
        asm volatile("s_waitcnt vmcnt(5)" ::: "memory");
        __builtin_amdgcn_s_barrier();
        READ_CVT(Bs0, As0)
        MFMA_ALL()
    }
    {   // k=15: final drain
        s16x8 bfr[4], af[4];
        asm volatile("s_waitcnt vmcnt(0)" ::: "memory");
        __builtin_amdgcn_s_barrier();
        READ_CVT(Bs1, As1)
        MFMA_ALL()
    }
#undef STAGE
#undef READ_CVT
#undef MFMA_ALL

    __syncthreads();                             // before sc_red overlay

    // ---- epilogue: full score rows (sc_red overlays smem) ----
    float* sc_red = (float*)smem;                // [8][64]
    const float* eqb = eq + b * NH;
    float vv[4], ee[4];
#pragma unroll
    for (int fc = 0; fc < 4; ++fc) {
        int c = wid * 64 + fc * 16 + lr;
        vv[fc] = v[c];
        ee[fc] = eqb[c];
    }
#pragma unroll
    for (int fr = 0; fr < 4; ++fr) {
#pragma unroll
        for (int reg = 0; reg < 4; ++reg) {
            float s = 0.f;
#pragma unroll
            for (int fc = 0; fc < 4; ++fc) {
                float x = acc[fr][fc][reg] + ee[fc];
                float t = 1.f - 2.f / (__expf(2.f * x) + 1.f);  // tanh
                s += vv[fc] * t;
            }
            s += __shfl_xor(s, 1);
            s += __shfl_xor(s, 2);
            s += __shfl_xor(s, 4);
            s += __shfl_xor(s, 8);
            if (lr == 0) sc_red[wid * 64 + fr * 16 + kq * 4 + reg] = s;
        }
    }
    __syncthreads();
    if (tid < 64) {
        float t = 0.f;
#pragma unroll
        for (int w = 0; w < 8; ++w) t += sc_red[w * 64 + tid];
        t *= SCALE;
        int rg = m0g + tid;
        if (mask[rg] != 0) t = -1e9f;
        out_sc[rg] = t;
    }
}

// ============================================================================
// k_smglp: softmax (from final scores) + glimpse slice. grid (16 sp, 32 b).
// ============================================================================
__global__ __launch_bounds__(256) void k_smglp(const float* __restrict__ scores,
                                               const float* __restrict__ ref,
                                               float* __restrict__ glp) {
    int sp = blockIdx.x, b = blockIdx.y;
    int tid = threadIdx.x;
    int lane = tid & 63, wid = tid >> 6;
    __shared__ float red[4];
    __shared__ float asl[128];    // unnormalized exp for rows sp*128..+128
    float sc[8];
    float mx = -3.4e38f;
#pragma unroll
    for (int i = 0; i < 8; ++i) {
        sc[i] = scores[b * NL + i * 256 + tid];
        mx = fmaxf(mx, sc[i]);
    }
#pragma unroll
    for (int o = 32; o >= 1; o >>= 1) mx = fmaxf(mx, __shfl_xor(mx, o));
    if (lane == 0) red[wid] = mx;
    __syncthreads();
    mx = fmaxf(fmaxf(red[0], red[1]), fmaxf(red[2], red[3]));
    __syncthreads();
    float ls = 0.f;
#pragma unroll
    for (int i = 0; i < 8; ++i) {
        float e = __expf(sc[i] - mx);
        ls += e;
        if (i == (sp >> 1) && (tid >> 7) == (sp & 1)) asl[tid & 127] = e;
    }
#pragma unroll
    for (int o = 32; o >= 1; o >>= 1) ls += __shfl_xor(ls, o);
    if (lane == 0) red[wid] = ls;
    __syncthreads();
    float inv = 1.f / (red[0] + red[1] + red[2] + red[3]);

    const float* rb = ref + ((size_t)b * NL + sp * 128) * NH;
    float2 acc = make_float2(0.f, 0.f);
#pragma unroll 4
    for (int l = 0; l < 128; ++l) {
        float a = asl[l];
        float2 r = ((const float2*)(rb + (size_t)l * NH))[tid];
        acc.x += a * r.x;
        acc.y += a * r.y;
    }
    acc.x *= inv;
    acc.y *= inv;
    ((float2*)(glp + (size_t)(sp * NB + b) * NH))[tid] = acc;
}

// ---- reduce glimpse partials (16 splits) ----
__global__ __launch_bounds__(256) void k_gred(const float* __restrict__ glp,
                                              float* __restrict__ out_gl) {
    int idx = blockIdx.x * 256 + threadIdx.x;   // 16384 = B*H
    float s = 0.f;
#pragma unroll
    for (int sp = 0; sp < 16; ++sp) s += glp[sp * (NB * NH) + idx];
    out_gl[idx] = s;
}

extern "C" void kernel_launch(void* const* d_in, const int* in_sizes, int n_in,
                              void* d_out, int out_size, void* d_ws, size_t ws_size,
                              hipStream_t stream) {
    const float* query = (const float*)d_in[0];
    const float* ref   = (const float*)d_in[1];
    const int*   mask  = (const int*)d_in[2];
    const float* W_ref = (const float*)d_in[3];
    const float* W_q   = (const float*)d_in[4];
    const float* v     = (const float*)d_in[5];

    float* out_gl = (float*)d_out;              // 32*512
    float* out_sc = out_gl + NB * NH;           // 32*2048 (final scores)

    char* w = (char*)d_ws;
    ushort* wW = (ushort*)w;                    // 524,288 B @ 0
    float* eq  = (float*)(w + 524288);          // 65,536 B
    float* glp = (float*)(w + 589824);          // 16*32*512*4 = 1,048,576 B

    k_pre<<<96, 256, 0, stream>>>(W_ref, wW, query, W_q, eq);
    k_gemm_full<<<1024, 512, 0, stream>>>(ref, wW, eq, v, mask, out_sc);
    k_smglp<<<dim3(16, NB), 256, 0, stream>>>(out_sc, ref, glp);
    k_gred<<<64, 256, 0, stream>>>(glp, out_gl);
}

// Round 11
// 120.569 us; speedup vs baseline: 1.0356x; 1.0009x over previous
//
#include <hip/hip_runtime.h>
#include <hip/hip_bf16.h>
#include <cstdint>

typedef __attribute__((ext_vector_type(4))) float f32x4;
typedef __attribute__((ext_vector_type(8))) short s16x8;

#define NB   32
#define NL   2048
#define NH   512
#define NM   (NB * NL)          // 65536 rows
#define SCALE 0.04419417382415922f  // 1/sqrt(512)

__device__ __forceinline__ ushort f2bf(float f) {
    __hip_bfloat16 b = __float2bfloat16(f);   // pairs fuse into v_cvt_pk_bf16_f32
    return *reinterpret_cast<ushort*>(&b);
}
__device__ __forceinline__ unsigned long long pack4(float4 f) {
    union { ushort u[4]; unsigned long long v; } p;
    p.u[0] = f2bf(f.x); p.u[1] = f2bf(f.y); p.u[2] = f2bf(f.z); p.u[3] = f2bf(f.w);
    return p.v;
}

// async global->LDS, 16B/lane: dest = wave-uniform base + lane*16; global addr per-lane
#define GL16(g, l)                                                         \
    __builtin_amdgcn_global_load_lds(                                      \
        (const __attribute__((address_space(1))) unsigned int*)(g),        \
        (__attribute__((address_space(3))) unsigned int*)(l), 16, 0, 0)

// ============================================================================
// k_pre: convW (blocks 0..63) + eq (blocks 64..95)
// ============================================================================
__global__ __launch_bounds__(256) void k_pre(const float* __restrict__ W,
                                             ushort* __restrict__ Wb,
                                             const float* __restrict__ query,
                                             const float* __restrict__ Wq,
                                             float* __restrict__ eq) {
    int bid = blockIdx.x;
    int t = threadIdx.x;
    if (bid < 64) {
        const float4* F = (const float4*)W;
        unsigned long long* U = (unsigned long long*)Wb;
        int base = bid * 1024 + t;
        float4 f[4];
#pragma unroll
        for (int k = 0; k < 4; ++k) f[k] = F[base + k * 256];
#pragma unroll
        for (int k = 0; k < 4; ++k) U[base + k * 256] = pack4(f[k]);
    } else {
        __shared__ float q[NH];
        int b = bid - 64;
        q[t] = query[b * NH + t];
        q[t + 256] = query[b * NH + t + 256];
        __syncthreads();
#pragma unroll
        for (int half = 0; half < 2; ++half) {
            int o = t + half * 256;
            const float4* w = (const float4*)(Wq + (size_t)o * NH);
            float acc = 0.f;
#pragma unroll 4
            for (int i = 0; i < NH / 4; ++i) {
                float4 x = w[i];
                acc += q[4 * i] * x.x + q[4 * i + 1] * x.y + q[4 * i + 2] * x.z + q[4 * i + 3] * x.w;
            }
            eq[b * NH + o] = acc;
        }
    }
}

// ============================================================================
// k_gemm_full v3: 1024 blocks x 256 thr (4 waves).
// BM=64, BN=512, BK=32, 16 K-steps. Wave tile 64 rows x 128 cols:
// 32 MFMA per 16 ds_read_b128 (2:1) -- halves LDS-pipe pressure vs R10.
// acc 4x8 f32x4 = 128 VGPR. launch_bounds(256,2) -> 2 blocks/CU, LDS 80 KB.
// Counted-vmcnt schedule (10 gl16/STAGE, never drain in loop), raw barriers,
// setprio around MFMA cluster. A staged f32 via gl16 (self-consistent swizzle),
// cvt to bf16 in-register after ds_read.
// ============================================================================
__global__ __launch_bounds__(256, 2) void k_gemm_full(const float* __restrict__ ref,
                                                      const ushort* __restrict__ Wb,
                                                      const float* __restrict__ eq,
                                                      const float* __restrict__ v,
                                                      const int* __restrict__ mask,
                                                      float* __restrict__ out_sc) {
    __shared__ char smem[81920];                 // 80 KB -> 2 blocks/CU
    ushort* Bs0 = (ushort*)smem;                 // 32 KB  [512][32] bf16
    ushort* Bs1 = (ushort*)(smem + 32768);       // 32 KB
    float*  As0 = (float*)(smem + 65536);        // 8 KB   [64][32] f32
    float*  As1 = (float*)(smem + 73728);        // 8 KB

    int tid = threadIdx.x;
    int lane = tid & 63, wid = tid >> 6;         // 4 waves
    int blk = blockIdx.x;
    int m0g = blk << 6;                          // 64 rows/block
    int b = blk >> 5;                            // batch (32 blocks/batch)

    f32x4 acc[4][8];
#pragma unroll
    for (int i = 0; i < 4; ++i)
#pragma unroll
        for (int j = 0; j < 8; ++j) acc[i][j] = (f32x4)(0.f);

    // ---- B staging: wave stages B rows wid*128..+128 (its own read cols) ----
    const ushort* bglob = Wb + ((size_t)(wid * 128) + (lane >> 2)) * NH + ((lane & 3) << 3);
    // ---- A staging: wave stages rows wid*16..+16; pre-swizzled chunk ----
    const float* aglob = ref + (size_t)(m0g + wid * 16 + (lane >> 3)) * NH
                             + (((lane & 7) ^ ((lane >> 3) & 7)) << 2);

    int lr = lane & 15, kq = lane >> 4;
    int bbase = (wid * 128 + lr) * 32 + (kq << 3);       // + fc*512
    int ac0 = (((2 * kq) ^ (lr & 7)) << 2);
    int ac1 = (((2 * kq + 1) ^ (lr & 7)) << 2);

#define STAGE(Bsb, Asb, kt)                                                \
    {   _Pragma("unroll")                                                  \
        for (int j = 0; j < 8; ++j)                                        \
            GL16(bglob + (kt) * 32 + j * 16 * NH,                          \
                 Bsb + (wid * 128 + j * 16) * 32);                         \
        GL16(aglob + (kt) * 32,          Asb + (wid * 16) * 32);           \
        GL16(aglob + (kt) * 32 + 8 * NH, Asb + (wid * 16 + 8) * 32); }

#define READ_CVT(Bsb, Asb)                                                       \
    _Pragma("unroll")                                                            \
    for (int f = 0; f < 8; ++f) bfr[f] = *(const s16x8*)&Bsb[bbase + f * 512];   \
    _Pragma("unroll")                                                            \
    for (int f = 0; f < 4; ++f) {                                                \
        float4 a0 = *(const float4*)(Asb + (f * 16 + lr) * 32 + ac0);            \
        float4 a1 = *(const float4*)(Asb + (f * 16 + lr) * 32 + ac1);            \
        union { ushort u[8]; s16x8 v; } p;                                       \
        p.u[0] = f2bf(a0.x); p.u[1] = f2bf(a0.y);                                \
        p.u[2] = f2bf(a0.z); p.u[3] = f2bf(a0.w);                                \
        p.u[4] = f2bf(a1.x); p.u[5] = f2bf(a1.y);                                \
        p.u[6] = f2bf(a1.z); p.u[7] = f2bf(a1.w);                                \
        af[f] = p.v;                                                             \
    }

#define MFMA_ALL()                                                               \
    __builtin_amdgcn_s_setprio(1);                                               \
    _Pragma("unroll")                                                            \
    for (int fr = 0; fr < 4; ++fr)                                               \
        _Pragma("unroll")                                                        \
        for (int fc = 0; fc < 8; ++fc)                                           \
            acc[fr][fc] = __builtin_amdgcn_mfma_f32_16x16x32_bf16(               \
                af[fr], bfr[fc], acc[fr][fc], 0, 0, 0);                          \
    __builtin_amdgcn_s_setprio(0);

    // prologue: two K-steps in flight (20 vmem ops/wave)
    STAGE(Bs0, As0, 0)
    STAGE(Bs1, As1, 1)

#pragma unroll 1
    for (int t2 = 0; t2 < 7; ++t2) {
        {   // phase A: compute k=2*t2 from buf0, restage buf0 with k+2
            s16x8 bfr[8], af[4];
            asm volatile("s_waitcnt vmcnt(10)" ::: "memory");
            __builtin_amdgcn_s_barrier();
            READ_CVT(Bs0, As0)
            asm volatile("s_waitcnt lgkmcnt(0)" ::: "memory");
            __builtin_amdgcn_sched_barrier(0);
            __builtin_amdgcn_s_barrier();
            STAGE(Bs0, As0, 2 * t2 + 2)
            MFMA_ALL()
        }
        {   // phase B: compute k=2*t2+1 from buf1, restage buf1 with k+3
            s16x8 bfr[8], af[4];
            asm volatile("s_waitcnt vmcnt(10)" ::: "memory");
            __builtin_amdgcn_s_barrier();
            READ_CVT(Bs1, As1)
            asm volatile("s_waitcnt lgkmcnt(0)" ::: "memory");
            __builtin_amdgcn_sched_barrier(0);
            __builtin_amdgcn_s_barrier();
            STAGE(Bs1, As1, 2 * t2 + 3)
            MFMA_ALL()
        }
    }
    {   // k=14: no restage
        s16x8 bfr[8], af[4];
        asm volatile("s_waitcnt vmcnt(10)" ::: "memory");
        __builtin_amdgcn_s_barrier();
        READ_CVT(Bs0, As0)
        MFMA_ALL()
    }
    {   // k=15: final drain
        s16x8 bfr[8], af[4];
        asm volatile("s_waitcnt vmcnt(0)" ::: "memory");
        __builtin_amdgcn_s_barrier();
        READ_CVT(Bs1, As1)
        MFMA_ALL()
    }
#undef STAGE
#undef READ_CVT
#undef MFMA_ALL

    __syncthreads();                             // before sc_red overlay

    // ---- epilogue: full score rows (sc_red overlays smem) ----
    float* sc_red = (float*)smem;                // [4][64]
    const float* eqb = eq + b * NH;
    float vv[8], ee[8];
#pragma unroll
    for (int fc = 0; fc < 8; ++fc) {
        int c = wid * 128 + fc * 16 + lr;
        vv[fc] = v[c];
        ee[fc] = eqb[c];
    }
#pragma unroll
    for (int fr = 0; fr < 4; ++fr) {
#pragma unroll
        for (int reg = 0; reg < 4; ++reg) {
            float s = 0.f;
#pragma unroll
            for (int fc = 0; fc < 8; ++fc) {
                float x = acc[fr][fc][reg] + ee[fc];
                float t = 1.f - 2.f / (__expf(2.f * x) + 1.f);  // tanh
                s += vv[fc] * t;
            }
            s += __shfl_xor(s, 1);
            s += __shfl_xor(s, 2);
            s += __shfl_xor(s, 4);
            s += __shfl_xor(s, 8);
            if (lr == 0) sc_red[wid * 64 + fr * 16 + kq * 4 + reg] = s;
        }
    }
    __syncthreads();
    if (tid < 64) {
        float t = 0.f;
#pragma unroll
        for (int w = 0; w < 4; ++w) t += sc_red[w * 64 + tid];
        t *= SCALE;
        int rg = m0g + tid;
        if (mask[rg] != 0) t = -1e9f;
        out_sc[rg] = t;
    }
}

// ============================================================================
// k_smglp: softmax (from final scores) + glimpse slice. grid (16 sp, 32 b).
// ============================================================================
__global__ __launch_bounds__(256) void k_smglp(const float* __restrict__ scores,
                                               const float* __restrict__ ref,
                                               float* __restrict__ glp) {
    int sp = blockIdx.x, b = blockIdx.y;
    int tid = threadIdx.x;
    int lane = tid & 63, wid = tid >> 6;
    __shared__ float red[4];
    __shared__ float asl[128];    // unnormalized exp for rows sp*128..+128
    float sc[8];
    float mx = -3.4e38f;
#pragma unroll
    for (int i = 0; i < 8; ++i) {
        sc[i] = scores[b * NL + i * 256 + tid];
        mx = fmaxf(mx, sc[i]);
    }
#pragma unroll
    for (int o = 32; o >= 1; o >>= 1) mx = fmaxf(mx, __shfl_xor(mx, o));
    if (lane == 0) red[wid] = mx;
    __syncthreads();
    mx = fmaxf(fmaxf(red[0], red[1]), fmaxf(red[2], red[3]));
    __syncthreads();
    float ls = 0.f;
#pragma unroll
    for (int i = 0; i < 8; ++i) {
        float e = __expf(sc[i] - mx);
        ls += e;
        if (i == (sp >> 1) && (tid >> 7) == (sp & 1)) asl[tid & 127] = e;
    }
#pragma unroll
    for (int o = 32; o >= 1; o >>= 1) ls += __shfl_xor(ls, o);
    if (lane == 0) red[wid] = ls;
    __syncthreads();
    float inv = 1.f / (red[0] + red[1] + red[2] + red[3]);

    const float* rb = ref + ((size_t)b * NL + sp * 128) * NH;
    float2 acc = make_float2(0.f, 0.f);
#pragma unroll 4
    for (int l = 0; l < 128; ++l) {
        float a = asl[l];
        float2 r = ((const float2*)(rb + (size_t)l * NH))[tid];
        acc.x += a * r.x;
        acc.y += a * r.y;
    }
    acc.x *= inv;
    acc.y *= inv;
    ((float2*)(glp + (size_t)(sp * NB + b) * NH))[tid] = acc;
}

// ---- reduce glimpse partials (16 splits) ----
__global__ __launch_bounds__(256) void k_gred(const float* __restrict__ glp,
                                              float* __restrict__ out_gl) {
    int idx = blockIdx.x * 256 + threadIdx.x;   // 16384 = B*H
    float s = 0.f;
#pragma unroll
    for (int sp = 0; sp < 16; ++sp) s += glp[sp * (NB * NH) + idx];
    out_gl[idx] = s;
}

extern "C" void kernel_launch(void* const* d_in, const int* in_sizes, int n_in,
                              void* d_out, int out_size, void* d_ws, size_t ws_size,
                              hipStream_t stream) {
    const float* query = (const float*)d_in[0];
    const float* ref   = (const float*)d_in[1];
    const int*   mask  = (const int*)d_in[2];
    const float* W_ref = (const float*)d_in[3];
    const float* W_q   = (const float*)d_in[4];
    const float* v     = (const float*)d_in[5];

    float* out_gl = (float*)d_out;              // 32*512
    float* out_sc = out_gl + NB * NH;           // 32*2048 (final scores)

    char* w = (char*)d_ws;
    ushort* wW = (ushort*)w;                    // 524,288 B @ 0
    float* eq  = (float*)(w + 524288);          // 65,536 B
    float* glp = (float*)(w + 589824);          // 16*32*512*4 = 1,048,576 B

    k_pre<<<96, 256, 0, stream>>>(W_ref, wW, query, W_q, eq);
    k_gemm_full<<<1024, 256, 0, stream>>>(ref, wW, eq, v, mask, out_sc);
    k_smglp<<<dim3(16, NB), 256, 0, stream>>>(out_sc, ref, glp);
    k_gred<<<64, 256, 0, stream>>>(glp, out_gl);
}